// Round 2
// baseline (5919.756 us; speedup 1.0000x reference)
//
#include <hip/hip_runtime.h>
#include <hip/hip_cooperative_groups.h>
#include <math.h>

namespace cg = cooperative_groups;

#define B 32
#define T 32
#define I_DIM 256
#define O_DIM 256
#define H_DIM 512
#define HS 64
#define MS 2048
#define NH 4
#define NCOL 516
#define NCOLP 520
#define NCH 16          // 128-row softmax sub-chunks

__device__ __forceinline__ float sigm(float x){ return 1.0f/(1.0f+__expf(-x)); }

// ---------- prep kernels (one-time, outside the loop) ----------
__global__ __launch_bounds__(256) void k_transpose_t(float* __restrict__ dst,
                                                     const float* __restrict__ src,
                                                     int N, int K){
  __shared__ float tile[32][33];
  int jb = blockIdx.x*32, kb = blockIdx.y*32;
  int tj = threadIdx.x & 31, tk = threadIdx.x >> 5;
  #pragma unroll
  for (int p = 0; p < 4; ++p){
    int j = jb + tk + p*8, k = kb + tj;
    if (j < N && k < K) tile[tk + p*8][tj] = src[j*K + k];
  }
  __syncthreads();
  #pragma unroll
  for (int p = 0; p < 4; ++p){
    int k = kb + tk + p*8, j = jb + tj;
    if (j < N && k < K) dst[k*N + j] = tile[tj][tk + p*8];
  }
}

__global__ __launch_bounds__(256) void k_gather_head(float* __restrict__ dst,
                                                     const float* __restrict__ W_head){
  int tid = blockIdx.x*256 + threadIdx.x;
  if (tid >= 512*NCOLP) return;
  int k = tid / NCOLP, col = tid % NCOLP;
  float v = 0.f;
  if (col < NCOL){
    int n = col/129, c = col%129;
    v = W_head[(n*2115 + c)*512 + k];
  }
  dst[tid] = v;
}

// ---------- persistent kernel ----------
struct Args {
  const float *x, *W_ih, *W_hh, *b_ih, *b_hh, *b_head, *b_out;
  const float *WT_HD, *WT_OUT;
  float *out, *MEM, *HF, *CF;
  float *SW, *PART, *PREAD, *HP, *WST, *READ, *HB0, *HB1, *HHIST, *RHIST;
};

union LS {
  struct { float4 wk4[4][16]; float gl[8][33]; } p1;
  struct { float red[256]; } p2;
  struct { float keys[8][64]; float mc[128][68]; float sc[8][128]; float red[8][32]; float cmx[8]; } p3;
  struct { float stats[8][2]; } p4;
  struct { float A[16][257]; } pout;
};

// Apply step-(t-1)'s memory update: mem[b][m][:] += sum_n ww[n][m] * wk[n][:]
// ww[n][m] = exp(sw[n][m] - gm[n]) * (st[n]/dn[n]).  256 blocks: b=bid>>3, 256 m-rows each.
__device__ __forceinline__ void do_upd(const Args& a, LS& ls, int bid, int tid){
  int b = bid >> 3, sub = bid & 7;
  if (tid < 64){
    int n = tid >> 4, e4 = tid & 15;
    const float* hp = a.HP + b*NCOLP + n*129 + 64 + e4*4;
    float4 v; v.x = hp[0]; v.y = hp[1]; v.z = hp[2]; v.w = hp[3];
    ls.p1.wk4[n][e4] = v;
  }
  float g[4], f[4];
  #pragma unroll
  for (int n = 0; n < 4; ++n){ g[n] = a.WST[b*8+n*2]; f[n] = a.WST[b*8+n*2+1]; }
  __syncthreads();
  int e4 = tid & 15, ms = tid >> 4;
  float4 k0 = ls.p1.wk4[0][e4], k1 = ls.p1.wk4[1][e4],
         k2 = ls.p1.wk4[2][e4], k3 = ls.p1.wk4[3][e4];
  const float* sw = a.SW + b*4*MS;
  #pragma unroll 2
  for (int it = 0; it < 16; ++it){
    int m = sub*256 + it*16 + ms;
    float w0 = __expf(sw[m]        - g[0])*f[0];
    float w1 = __expf(sw[MS+m]     - g[1])*f[1];
    float w2 = __expf(sw[2*MS+m]   - g[2])*f[2];
    float w3 = __expf(sw[3*MS+m]   - g[3])*f[3];
    float4* p = (float4*)a.MEM + (b*MS + m)*16 + e4;
    float4 v = *p;
    v.x += w0*k0.x + w1*k1.x + w2*k2.x + w3*k3.x;
    v.y += w0*k0.y + w1*k1.y + w2*k2.y + w3*k3.y;
    v.z += w0*k0.z + w1*k1.z + w2*k2.z + w3*k3.z;
    v.w += w0*k0.w + w1*k1.w + w2*k2.w + w3*k3.w;
    *p = v;
  }
  __syncthreads();
}

__global__ __launch_bounds__(256, 1) void ntm_persist(Args a){
  cg::grid_group grid = cg::this_grid();
  const int bid = blockIdx.x, tid = threadIdx.x;
  __shared__ LS ls;

  for (int t = 0; t < T; ++t){
    float* hcur = (t & 1) ? a.HB1 : a.HB0;
    float* hnxt = (t & 1) ? a.HB0 : a.HB1;

    // ---- P1: deferred mem update (t-1) + gates GEMM + LSTM ----
    if (t > 0) do_upd(a, ls, bid, tid);
    {
      int b = tid & 31, rsub = tid >> 5;       // 8 rows per block
      int gate = rsub & 3, jj = rsub >> 2;
      int j = bid*2 + jj;
      int row = gate*512 + j;
      const float4* wih4 = (const float4*)a.W_ih + row*128;
      const float4* whh4 = (const float4*)a.W_hh + row*128;
      const float4* xin4 = (const float4*)a.x + (b*T + t)*64;
      const float4* rd4  = (const float4*)a.READ + b*64;
      const float4* h4   = (const float4*)hcur + b*128;
      float acc = 0.f;
      #pragma unroll 4
      for (int k4 = 0; k4 < 64; ++k4){
        float4 w = wih4[k4], v = xin4[k4];
        acc += w.x*v.x + w.y*v.y + w.z*v.z + w.w*v.w;
      }
      #pragma unroll 4
      for (int k4 = 0; k4 < 64; ++k4){
        float4 w = wih4[64+k4], v = rd4[k4];
        acc += w.x*v.x + w.y*v.y + w.z*v.z + w.w*v.w;
      }
      #pragma unroll 4
      for (int k4 = 0; k4 < 128; ++k4){
        float4 w = whh4[k4], v = h4[k4];
        acc += w.x*v.x + w.y*v.y + w.z*v.z + w.w*v.w;
      }
      acc += a.b_ih[row] + a.b_hh[row];
      ls.p1.gl[rsub][b] = acc;
      __syncthreads();
      if (tid < 64){
        int b2 = tid & 31, jj2 = tid >> 5;
        int j2 = bid*2 + jj2;
        float gi = ls.p1.gl[jj2*4+0][b2], gf = ls.p1.gl[jj2*4+1][b2];
        float gg = ls.p1.gl[jj2*4+2][b2], go = ls.p1.gl[jj2*4+3][b2];
        float c = sigm(gf)*a.CF[b2*512+j2] + sigm(gi)*tanhf(gg);
        float h = sigm(go)*tanhf(c);
        a.CF[b2*512+j2] = c;
        hnxt[b2*512+j2] = h;
        a.HHIST[(t*B + b2)*512 + j2] = h;
      }
    }
    grid.sync();

    // ---- P2: head projection, used cols only (129 blocks x 4 cols) ----
    if (bid < 129){
      int cs = tid & 3, bsub = (tid >> 2) & 31, half = tid >> 7;
      int col = bid*4 + cs;
      int k0 = half*256;
      const float* hrow = hnxt + bsub*512 + k0;
      const float* wcol = a.WT_HD + k0*NCOLP + col;
      float acc = 0.f;
      #pragma unroll 4
      for (int k = 0; k < 256; ++k) acc += hrow[k] * wcol[k*NCOLP];
      ls.p2.red[tid] = acc;
      __syncthreads();
      if (half == 0){
        float v = acc + ls.p2.red[tid + 128];
        if (col < NCOL){ int n = col/129, c = col%129; v += a.b_head[n*2115 + c]; }
        else v = 0.f;
        a.HP[bsub*NCOLP + col] = v;
      }
    }
    grid.sync();

    // ---- P3: scores + chunk softmax partials + partial reads ----
    {
      int b = bid >> 3, ch8 = bid & 7;
      for (int idx = tid; idx < 512; idx += 256){
        int kk = idx >> 6, e = idx & 63;
        int n = kk & 3;
        int c = (kk >= 4) ? (64 + e) : e;
        ls.p3.keys[kk][e] = a.HP[b*NCOLP + n*129 + c];
      }
      for (int sub = 0; sub < 2; ++sub){
        int ch = ch8*2 + sub;
        __syncthreads();
        for (int idx = tid; idx < 128*16; idx += 256){
          int m = idx >> 4, e4 = idx & 15;
          ((float4*)&ls.p3.mc[m][0])[e4] =
              ((const float4*)a.MEM)[(b*MS + ch*128 + m)*16 + e4];
        }
        __syncthreads();
        {
          int m = tid & 127, kp = tid >> 7;
          const float4* mrow4 = (const float4*)&ls.p3.mc[m][0];
          float s0=0.f, s1=0.f, s2=0.f, s3=0.f;
          #pragma unroll 4
          for (int e4 = 0; e4 < 16; ++e4){
            float4 mv = mrow4[e4];
            float4 ka = *(const float4*)&ls.p3.keys[kp*4+0][e4*4];
            float4 kb = *(const float4*)&ls.p3.keys[kp*4+1][e4*4];
            float4 kc = *(const float4*)&ls.p3.keys[kp*4+2][e4*4];
            float4 kd = *(const float4*)&ls.p3.keys[kp*4+3][e4*4];
            s0 += mv.x*ka.x + mv.y*ka.y + mv.z*ka.z + mv.w*ka.w;
            s1 += mv.x*kb.x + mv.y*kb.y + mv.z*kb.z + mv.w*kb.w;
            s2 += mv.x*kc.x + mv.y*kc.y + mv.z*kc.z + mv.w*kc.w;
            s3 += mv.x*kd.x + mv.y*kd.y + mv.z*kd.z + mv.w*kd.w;
          }
          s0 *= 0.125f; s1 *= 0.125f; s2 *= 0.125f; s3 *= 0.125f;
          ls.p3.sc[kp*4+0][m] = s0; ls.p3.sc[kp*4+1][m] = s1;
          ls.p3.sc[kp*4+2][m] = s2; ls.p3.sc[kp*4+3][m] = s3;
          if (kp){
            float* swp = a.SW + b*4*MS + ch*128 + m;
            swp[0] = s0; swp[MS] = s1; swp[2*MS] = s2; swp[3*MS] = s3;
          }
        }
        __syncthreads();
        {
          int kk = tid >> 5, j = tid & 31;
          float mx = ls.p3.sc[kk][j];
          mx = fmaxf(mx, ls.p3.sc[kk][j+32]);
          mx = fmaxf(mx, ls.p3.sc[kk][j+64]);
          mx = fmaxf(mx, ls.p3.sc[kk][j+96]);
          ls.p3.red[kk][j] = mx;
        }
        __syncthreads();
        if (tid < 8){
          float mx = ls.p3.red[tid][0];
          for (int j=1;j<32;++j) mx = fmaxf(mx, ls.p3.red[tid][j]);
          ls.p3.cmx[tid] = mx;
        }
        __syncthreads();
        {
          int kk = tid >> 5, j = tid & 31;
          float m0 = ls.p3.cmx[kk];
          float se = 0.f;
          #pragma unroll
          for (int i=0;i<4;++i){
            int m = j + i*32;
            float e0 = __expf(ls.p3.sc[kk][m] - m0);
            se += e0;
            if (kk < 4) ls.p3.sc[kk][m] = e0;
          }
          ls.p3.red[kk][j] = se;
        }
        __syncthreads();
        if (tid < 8){
          float s = 0.f;
          for (int j=0;j<32;++j) s += ls.p3.red[tid][j];
          a.PART[((b*NCH+ch)*8 + tid)*2]     = ls.p3.cmx[tid];
          a.PART[((b*NCH+ch)*8 + tid)*2 + 1] = s;
        }
        {
          int n = tid >> 6, e = tid & 63;
          float pr = 0.f;
          for (int m = 0; m < 128; ++m) pr += ls.p3.sc[n][m] * ls.p3.mc[m][e];
          a.PREAD[((b*NCH+ch)*4 + n)*64 + e] = pr;
        }
      }
    }
    grid.sync();

    // ---- P4: merge softmax, finalize read, write-weight stats ----
    if (bid < 32){
      int b = bid;
      if (tid < 8){
        float mx = -1e30f;
        for (int c = 0; c < NCH; ++c)
          mx = fmaxf(mx, a.PART[((b*NCH+c)*8+tid)*2]);
        float d = 0.f;
        for (int c = 0; c < NCH; ++c)
          d += a.PART[((b*NCH+c)*8+tid)*2+1] * __expf(a.PART[((b*NCH+c)*8+tid)*2] - mx);
        ls.p4.stats[tid][0] = mx; ls.p4.stats[tid][1] = d;
      }
      __syncthreads();
      {
        int n = tid >> 6, e = tid & 63;
        float gmn = ls.p4.stats[n][0], dnn = ls.p4.stats[n][1];
        float r = 0.f;
        for (int c = 0; c < NCH; ++c)
          r += a.PREAD[((b*NCH+c)*4+n)*64+e] * __expf(a.PART[((b*NCH+c)*8+n)*2] - gmn);
        r /= dnn;
        a.READ[b*256 + n*64 + e] = r;
        a.RHIST[(t*B + b)*256 + n*64 + e] = r;
      }
      if (tid < 4){
        float st = sigm(a.HP[b*NCOLP + tid*129 + 128]);
        a.WST[b*8 + tid*2]     = ls.p4.stats[4+tid][0];
        a.WST[b*8 + tid*2 + 1] = st / ls.p4.stats[4+tid][1];
      }
    }
    grid.sync();
  }

  // ---- final: flush last mem update, copy h, batched output GEMM ----
  do_upd(a, ls, bid, tid);
  if (bid < 16){
    int i = bid*256 + tid;
    ((float4*)a.HF)[i] = ((const float4*)a.HB0)[i];   // T even -> final h in HB0
  }
  {
    int nt = bid & 3, mt = bid >> 2;      // 4 col-tiles x 64 row-tiles of 16
    int rl = tid & 15, og = tid >> 4;
    int o = nt*64 + og*4;
    float acc[4] = {0.f,0.f,0.f,0.f};
    for (int kc = 0; kc < 3; ++kc){
      __syncthreads();
      for (int idx = tid; idx < 16*256; idx += 256){
        int r = idx >> 8, k = idx & 255;
        int kg = kc*256 + k;
        int row = mt*16 + r;
        int bb = row >> 5, tt = row & 31;
        float v = (kg < 512) ? a.HHIST[(tt*B + bb)*512 + kg]
                             : a.RHIST[(tt*B + bb)*256 + (kg - 512)];
        ls.pout.A[r][k] = v;
      }
      __syncthreads();
      const float* Ar = &ls.pout.A[rl][0];
      #pragma unroll 4
      for (int k = 0; k < 256; ++k){
        float av = Ar[k];
        float4 w = *(const float4*)(a.WT_OUT + (kc*256+k)*O_DIM + o);
        acc[0] += av*w.x; acc[1] += av*w.y; acc[2] += av*w.z; acc[3] += av*w.w;
      }
    }
    int row = mt*16 + rl;
    float4 bo = *(const float4*)(a.b_out + o);
    float4 res; res.x = acc[0]+bo.x; res.y = acc[1]+bo.y;
    res.z = acc[2]+bo.z; res.w = acc[3]+bo.w;
    *(float4*)(a.out + row*O_DIM + o) = res;
  }
}

extern "C" void kernel_launch(void* const* d_in, const int* in_sizes, int n_in,
                              void* d_out, int out_size, void* d_ws, size_t ws_size,
                              hipStream_t stream)
{
  const float* x      = (const float*)d_in[0];
  const float* W_ih   = (const float*)d_in[1];
  const float* W_hh   = (const float*)d_in[2];
  const float* b_ih   = (const float*)d_in[3];
  const float* b_hh   = (const float*)d_in[4];
  const float* W_head = (const float*)d_in[5];
  const float* b_head = (const float*)d_in[6];
  const float* W_out  = (const float*)d_in[7];
  const float* b_out  = (const float*)d_in[8];

  float* out = (float*)d_out;
  float* MEM = out + B*T*O_DIM;
  float* HF  = MEM + B*MS*HS;
  float* CF  = HF + B*H_DIM;

  float* ws     = (float*)d_ws;
  float* WT_HD  = ws;                      // 512*520
  float* WT_OUT = WT_HD  + 512*NCOLP;      // 768*256
  float* SW     = WT_OUT + 768*256;        // 32*4*2048
  float* PART   = SW     + B*4*MS;         // 32*16*8*2
  float* PREAD  = PART   + B*NCH*16;       // 32*16*4*64
  float* HP     = PREAD  + B*NCH*4*64;     // 32*520
  float* WST    = HP     + B*NCOLP;        // 32*8
  float* READ   = WST    + B*8;            // 32*256
  float* HB0    = READ   + B*256;          // 32*512
  float* HB1    = HB0    + B*H_DIM;        // 32*512
  float* HHIST  = HB1    + B*H_DIM;        // 32*32*512
  float* RHIST  = HHIST  + T*B*512;        // 32*32*256

  hipMemsetAsync(MEM, 0, (size_t)(B*MS*HS + 2*B*H_DIM)*sizeof(float), stream);
  hipMemsetAsync(READ, 0, (size_t)(B*256 + 2*B*H_DIM)*sizeof(float), stream);

  k_transpose_t<<<dim3(8, 24), 256, 0, stream>>>(WT_OUT, W_out, 256, 768);
  k_gather_head<<<(512*NCOLP + 255)/256, 256, 0, stream>>>(WT_HD, W_head);

  Args a;
  a.x = x; a.W_ih = W_ih; a.W_hh = W_hh; a.b_ih = b_ih; a.b_hh = b_hh;
  a.b_head = b_head; a.b_out = b_out;
  a.WT_HD = WT_HD; a.WT_OUT = WT_OUT;
  a.out = out; a.MEM = MEM; a.HF = HF; a.CF = CF;
  a.SW = SW; a.PART = PART; a.PREAD = PREAD; a.HP = HP; a.WST = WST;
  a.READ = READ; a.HB0 = HB0; a.HB1 = HB1; a.HHIST = HHIST; a.RHIST = RHIST;

  void* kp[] = { (void*)&a };
  hipLaunchCooperativeKernel((const void*)ntm_persist, dim3(256), dim3(256),
                             kp, 0, stream);
}

// Round 6
// 1755.863 us; speedup vs baseline: 3.3714x; 3.3714x over previous
//
#include <hip/hip_runtime.h>
#include <math.h>

#define B 32
#define T 32
#define O_DIM 256
#define H_DIM 512
#define HS 64
#define MS 2048
#define NCOL 516
#define NCH 32          // 64-row softmax chunks

typedef __attribute__((ext_vector_type(4))) float f4;

__device__ __forceinline__ float sigm(float x){ return 1.0f/(1.0f+__expf(-x)); }
__device__ __forceinline__ float hsum(f4 v){ return (v.x + v.y) + (v.z + v.w); }

// ---------------- prep kernels ----------------
__global__ __launch_bounds__(256) void k_transpose_t(float* __restrict__ dst,
                                                     const float* __restrict__ src,
                                                     int N, int K){
  __shared__ float tile[32][33];
  int jb = blockIdx.x*32, kb = blockIdx.y*32;
  int tj = threadIdx.x & 31, tk = threadIdx.x >> 5;
  #pragma unroll
  for (int p = 0; p < 4; ++p){
    int j = jb + tk + p*8, k = kb + tj;
    if (j < N && k < K) tile[tk + p*8][tj] = src[j*K + k];
  }
  __syncthreads();
  #pragma unroll
  for (int p = 0; p < 4; ++p){
    int k = kb + tk + p*8, j = jb + tj;
    if (j < N && k < K) dst[k*N + j] = tile[tj][tk + p*8];
  }
}

__global__ __launch_bounds__(256) void k_ghead(float* __restrict__ dst,
                                               const float* __restrict__ W_head){
  int idx = blockIdx.x*256 + threadIdx.x;     // col*512 + k
  if (idx >= 520*512) return;
  int col = idx >> 9, k = idx & 511;
  float v = 0.f;
  if (col < NCOL){ int n = col/129, c = col%129; v = W_head[((size_t)n*2115 + c)*512 + k]; }
  dst[idx] = v;
}

__global__ __launch_bounds__(256) void k_xt(f4* __restrict__ XT4,
                                            const float* __restrict__ x){
  int idx = blockIdx.x*256 + threadIdx.x;     // t*2048 + k4*32 + b
  int b = idx & 31, k4 = (idx >> 5) & 63, t = idx >> 11;
  XT4[idx] = ((const f4*)x)[(size_t)(b*T + t)*64 + k4];
}

// ---------------- PH_A: gates GEMM + LSTM (256 blocks) ----------------
__global__ __launch_bounds__(256) void k_A(
    const f4* __restrict__ XT4, const float* __restrict__ W_ih,
    const float* __restrict__ W_hh, const float* __restrict__ b_ih,
    const float* __restrict__ b_hh, const f4* __restrict__ READT4,
    float* __restrict__ HHT, float* __restrict__ CF, int t)
{
  __shared__ float gl[8][33];
  const int bid = blockIdx.x, tid = threadIdx.x;
  const f4* HHT4 = (const f4*)HHT;
  {
    int b = tid & 31, rsub = tid >> 5;
    int gate = rsub & 3, jj = rsub >> 2;
    int row = gate*512 + bid*2 + jj;
    const f4* wih4 = (const f4*)W_ih + (size_t)row*128;
    const f4* whh4 = (const f4*)W_hh + (size_t)row*128;
    const f4* xt4 = XT4 + (size_t)t*2048;
    f4 acc4 = {0.f, 0.f, 0.f, 0.f};
    #pragma unroll 4
    for (int k4 = 0; k4 < 64; ++k4)
      acc4 += wih4[k4] * xt4[k4*32 + b];
    #pragma unroll 4
    for (int k4 = 0; k4 < 64; ++k4)
      acc4 += wih4[64 + k4] * READT4[k4*32 + b];
    if (t > 0){
      const f4* ht4 = HHT4 + (size_t)(t-1)*4096;
      #pragma unroll 4
      for (int k4 = 0; k4 < 128; ++k4)
        acc4 += whh4[k4] * ht4[k4*32 + b];
    }
    float acc = hsum(acc4) + b_ih[row] + b_hh[row];
    gl[rsub][b] = acc;
  }
  __syncthreads();
  if (tid < 64){
    int b2 = tid & 31, jj2 = tid >> 5;
    int j2 = bid*2 + jj2;
    float gi = gl[jj2*4+0][b2], gf = gl[jj2*4+1][b2];
    float gg = gl[jj2*4+2][b2], go = gl[jj2*4+3][b2];
    float c = sigm(gf)*CF[b2*512+j2] + sigm(gi)*tanhf(gg);
    float h = sigm(go)*tanhf(c);
    CF[b2*512+j2] = c;
    HHT[((size_t)t*128 + (j2>>2))*128 + b2*4 + (j2&3)] = h;
  }
}

// ---------------- PH_B: head projection (130 blocks) ----------------
__global__ __launch_bounds__(256) void k_B(
    const float* __restrict__ HHT, const float* __restrict__ WT_HD2,
    const float* __restrict__ b_head, float* __restrict__ HPT, int t)
{
  __shared__ float red[256];
  const int bid = blockIdx.x, tid = threadIdx.x;
  const f4* HHT4 = (const f4*)HHT;
  int b = tid & 31, cs = (tid>>5)&3, khalf = tid>>7;
  int col = bid*4 + cs;
  const f4* hT4 = HHT4 + (size_t)t*4096 + khalf*2048;
  const f4* w4  = (const f4*)(WT_HD2 + (size_t)col*512 + khalf*256);
  f4 acc4 = {0.f, 0.f, 0.f, 0.f};
  #pragma unroll 4
  for (int k4 = 0; k4 < 64; ++k4)
    acc4 += w4[k4] * hT4[k4*32 + b];
  red[tid] = hsum(acc4);
  __syncthreads();
  if (khalf == 0){
    float v = red[tid] + red[tid + 128];
    if (col < NCOL){ int n = col/129, c = col%129; v += b_head[n*2115 + c]; }
    HPT[col*32 + b] = v;
  }
}

// ---------------- PH_C: scores + chunk partials + partial reads (256 blocks) ----------------
__global__ __launch_bounds__(256) void k_C(
    const float* __restrict__ MEM, const float* __restrict__ HPT,
    float* __restrict__ SW, float* __restrict__ PART, float* __restrict__ PREAD)
{
  __shared__ float keys[8][64];
  __shared__ float mc[64][68];
  __shared__ float sc[8][64];
  __shared__ float red[8][32];
  __shared__ float cmx[8];
  const int bid = blockIdx.x, tid = threadIdx.x;
  const f4* MEM4 = (const f4*)MEM;
  int xcd = bid & 7, t2 = bid >> 3;
  int b = xcd*4 + (t2 & 3), ch8 = t2 >> 2;
  for (int idx = tid; idx < 512; idx += 256){
    int kk = idx >> 6, e = idx & 63;
    int n = kk & 3;
    int c = (kk >= 4) ? (64 + e) : e;
    keys[kk][e] = HPT[(n*129 + c)*32 + b];
  }
  for (int sub = 0; sub < 4; ++sub){
    int ch = ch8*4 + sub;
    __syncthreads();
    for (int idx = tid; idx < 64*16; idx += 256){
      int m = idx >> 4, e4 = idx & 15;
      ((f4*)&mc[m][0])[e4] = MEM4[((size_t)b*MS + ch*64 + m)*16 + e4];
    }
    __syncthreads();
    {
      int m = tid & 63, kp = tid >> 6;
      const f4* mrow4 = (const f4*)&mc[m][0];
      int k0 = kp*2, k1 = kp*2+1;
      f4 s0v = {0.f,0.f,0.f,0.f}, s1v = {0.f,0.f,0.f,0.f};
      #pragma unroll 4
      for (int e4 = 0; e4 < 16; ++e4){
        f4 mv = mrow4[e4];
        s0v += mv * (*(const f4*)&keys[k0][e4*4]);
        s1v += mv * (*(const f4*)&keys[k1][e4*4]);
      }
      float s0 = hsum(s0v)*0.125f, s1 = hsum(s1v)*0.125f;
      sc[k0][m] = s0; sc[k1][m] = s1;
      if (kp >= 2){
        float* swp = SW + ((size_t)b*4 + (k0-4))*MS + ch*64 + m;
        swp[0] = s0; swp[MS] = s1;
      }
    }
    __syncthreads();
    {
      int kk = tid >> 5, j = tid & 31;
      red[kk][j] = fmaxf(sc[kk][j], sc[kk][j+32]);
    }
    __syncthreads();
    if (tid < 8){
      float mx = red[tid][0];
      for (int j = 1; j < 32; ++j) mx = fmaxf(mx, red[tid][j]);
      cmx[tid] = mx;
    }
    __syncthreads();
    {
      int kk = tid >> 5, j = tid & 31;
      float m0 = cmx[kk];
      float e0 = __expf(sc[kk][j] - m0);
      float e1 = __expf(sc[kk][j+32] - m0);
      if (kk < 4){ sc[kk][j] = e0; sc[kk][j+32] = e1; }
      red[kk][j] = e0 + e1;
    }
    __syncthreads();
    if (tid < 8){
      float s = 0.f;
      for (int j = 0; j < 32; ++j) s += red[tid][j];
      float* pp = PART + (((size_t)b*NCH + ch)*8 + tid)*2;
      pp[0] = cmx[tid]; pp[1] = s;
    }
    {
      int n = tid >> 6, e = tid & 63;
      float pr = 0.f;
      for (int m = 0; m < 64; ++m) pr += sc[n][m] * mc[m][e];
      PREAD[(((size_t)b*NCH + ch)*4 + n)*64 + e] = pr;
    }
  }
}

// ---------------- PH_D: mem update + read merge + HF copy (256 blocks) ----------------
__global__ __launch_bounds__(256) void k_D(
    float* __restrict__ MEM, const float* __restrict__ HPT,
    const float* __restrict__ SW, const float* __restrict__ PART,
    const float* __restrict__ PREAD, float* __restrict__ READT,
    float* __restrict__ RHIST, const float* __restrict__ HHT,
    float* __restrict__ HF, int t)
{
  __shared__ float gm[4], fac[4];
  __shared__ f4 wk4[4][16];
  __shared__ float ew[4][256];
  __shared__ float gm2[4], dn2[4];
  const int bid = blockIdx.x, tid = threadIdx.x;
  const f4* HHT4 = (const f4*)HHT;
  int xcd = bid & 7, t2 = bid >> 3;
  int b = xcd*4 + (t2 & 3), sub = t2 >> 2;
  if (tid < 4){
    int kk = 4 + tid;
    const float* pp = PART + ((size_t)b*NCH*8 + kk)*2;
    float mx = -1e30f;
    for (int ch = 0; ch < NCH; ++ch) mx = fmaxf(mx, pp[ch*16]);
    float d = 0.f;
    for (int ch = 0; ch < NCH; ++ch) d += pp[ch*16+1]*__expf(pp[ch*16] - mx);
    float st = sigm(HPT[(tid*129 + 128)*32 + b]);
    gm[tid] = mx;
    fac[tid] = st / d;
  }
  if (tid < 64){
    int n = tid >> 4, e4 = tid & 15;
    f4 v;
    v.x = HPT[(n*129+64+e4*4+0)*32 + b];
    v.y = HPT[(n*129+64+e4*4+1)*32 + b];
    v.z = HPT[(n*129+64+e4*4+2)*32 + b];
    v.w = HPT[(n*129+64+e4*4+3)*32 + b];
    wk4[n][e4] = v;
  }
  __syncthreads();
  for (int idx = tid; idx < 1024; idx += 256){
    int n = idx >> 8, m = idx & 255;
    float s = SW[((size_t)b*4 + n)*MS + sub*256 + m];
    ew[n][m] = __expf(s - gm[n]) * fac[n];
  }
  __syncthreads();
  {
    int e4 = tid & 15, ms = tid >> 4;
    f4 k0 = wk4[0][e4], k1 = wk4[1][e4], k2 = wk4[2][e4], k3 = wk4[3][e4];
    #pragma unroll 2
    for (int it = 0; it < 16; ++it){
      int m = it*16 + ms;
      float w0 = ew[0][m], w1 = ew[1][m];
      float w2 = ew[2][m], w3 = ew[3][m];
      f4* p = (f4*)MEM + ((size_t)b*MS + sub*256 + m)*16 + e4;
      f4 v = *p;
      v += w0*k0 + w1*k1 + w2*k2 + w3*k3;
      *p = v;
    }
  }
  if (bid < 32){
    int bb = bid;
    __syncthreads();
    if (tid < 4){
      const float* pp = PART + ((size_t)bb*NCH*8 + tid)*2;
      float mx = -1e30f;
      for (int ch = 0; ch < NCH; ++ch) mx = fmaxf(mx, pp[ch*16]);
      float d = 0.f;
      for (int ch = 0; ch < NCH; ++ch) d += pp[ch*16+1]*__expf(pp[ch*16] - mx);
      gm2[tid] = mx; dn2[tid] = d;
    }
    __syncthreads();
    int n = tid >> 6, e = tid & 63;
    float gmn = gm2[n], dnn = dn2[n];
    float r = 0.f;
    for (int ch = 0; ch < NCH; ++ch){
      float cm = PART[(((size_t)bb*NCH + ch)*8 + n)*2];
      r += PREAD[(((size_t)bb*NCH + ch)*4 + n)*64 + e] * __expf(cm - gmn);
    }
    r /= dnn;
    int k = n*64 + e;
    READT[(k>>2)*128 + bb*4 + (k&3)] = r;
    RHIST[((size_t)t*64 + (k>>2))*128 + bb*4 + (k&3)] = r;
  }
  if (t == T-1 && bid >= 32 && bid < 48){
    int blk = bid - 32;
    int j4 = tid & 127, bb = (tid >> 7) + blk*2;
    ((f4*)HF)[(size_t)bb*128 + j4] = HHT4[((size_t)(T-1)*128 + j4)*32 + bb];
  }
}

// ---------------- final output GEMM (256 blocks) ----------------
__global__ __launch_bounds__(256) void k_out(
    const float* __restrict__ HHT, const float* __restrict__ RHIST,
    const float* __restrict__ WT_OUT, const float* __restrict__ b_out,
    float* __restrict__ out)
{
  __shared__ float A[16][260];
  const int bid = blockIdx.x, tid = threadIdx.x;
  const f4* HHT4 = (const f4*)HHT;
  const f4* RHIST4 = (const f4*)RHIST;
  int nt = bid & 3, mt = bid >> 2;
  int rl = tid & 15, og = tid >> 4;
  int o = nt*64 + og*4;
  f4 accv = {0.f,0.f,0.f,0.f};
  for (int kc = 0; kc < 3; ++kc){
    __syncthreads();
    for (int idx = tid; idx < 1024; idx += 256){
      int r = idx >> 6, k4 = idx & 63;
      int row = mt*16 + r;
      int bb = row >> 5, tt = row & 31;
      int kg4 = kc*64 + k4;
      f4 v = (kg4 < 128)
        ? HHT4[((size_t)tt*128 + kg4)*32 + bb]
        : RHIST4[((size_t)tt*64 + (kg4-128))*32 + bb];
      *(f4*)&A[r][k4*4] = v;
    }
    __syncthreads();
    const float* Ar = &A[rl][0];
    #pragma unroll 4
    for (int k = 0; k < 256; ++k){
      float av = Ar[k];
      accv += av * (*(const f4*)(WT_OUT + ((size_t)kc*256 + k)*O_DIM + o));
    }
  }
  int row = mt*16 + rl;
  accv += *(const f4*)(b_out + o);
  *(f4*)(out + (size_t)row*O_DIM + o) = accv;
}

extern "C" void kernel_launch(void* const* d_in, const int* in_sizes, int n_in,
                              void* d_out, int out_size, void* d_ws, size_t ws_size,
                              hipStream_t stream)
{
  const float* x      = (const float*)d_in[0];
  const float* W_ih   = (const float*)d_in[1];
  const float* W_hh   = (const float*)d_in[2];
  const float* b_ih   = (const float*)d_in[3];
  const float* b_hh   = (const float*)d_in[4];
  const float* W_head = (const float*)d_in[5];
  const float* b_head = (const float*)d_in[6];
  const float* W_out  = (const float*)d_in[7];
  const float* b_out  = (const float*)d_in[8];

  float* out = (float*)d_out;
  float* MEM = out + B*T*O_DIM;
  float* HF  = MEM + (size_t)B*MS*HS;
  float* CF  = HF + B*H_DIM;

  float* ws      = (float*)d_ws;
  float* WT_HD2  = ws;                          // 520*512   = 266240
  float* WT_OUT  = WT_HD2 + 520*512;            // 768*256   = 196608
  float* XT      = WT_OUT + 768*256;            // 262144
  float* SW      = XT     + 262144;             // 32*4*2048 = 262144
  float* PART    = SW     + 262144;             // 32*32*8*2 = 16384
  float* PREAD   = PART   + 16384;              // 32*32*4*64= 262144
  float* HPT     = PREAD  + 262144;             // 520*32    = 16640
  float* READT   = HPT    + 16640;              // 256*32    = 8192
  float* HHT     = READT  + 8192;               // 32*512*32 = 524288
  float* RHIST   = HHT    + 524288;             // 32*256*32 = 262144

  (void)hipMemsetAsync(MEM, 0, ((size_t)B*MS*HS + 2*B*H_DIM)*sizeof(float), stream);
  (void)hipMemsetAsync(READT, 0, (size_t)8192*sizeof(float), stream);

  k_ghead<<<1040, 256, 0, stream>>>(WT_HD2, W_head);
  k_transpose_t<<<dim3(8, 24), 256, 0, stream>>>(WT_OUT, W_out, 256, 768);
  k_xt<<<256, 256, 0, stream>>>((f4*)XT, x);

  for (int t = 0; t < T; ++t){
    k_A<<<256, 256, 0, stream>>>((const f4*)XT, W_ih, W_hh, b_ih, b_hh,
                                 (const f4*)READT, HHT, CF, t);
    k_B<<<130, 256, 0, stream>>>(HHT, WT_HD2, b_head, HPT, t);
    k_C<<<256, 256, 0, stream>>>(MEM, HPT, SW, PART, PREAD);
    k_D<<<256, 256, 0, stream>>>(MEM, HPT, SW, PART, PREAD, READT, RHIST,
                                 HHT, HF, t);
  }
  k_out<<<256, 256, 0, stream>>>(HHT, RHIST, WT_OUT, b_out, out);
}

// Round 7
// 1470.985 us; speedup vs baseline: 4.0243x; 1.1937x over previous
//
#include <hip/hip_runtime.h>
#include <math.h>

#define B 32
#define T 32
#define O_DIM 256
#define H_DIM 512
#define HS 64
#define MS 2048
#define NCOL 516
#define NCH 32          // 64-row softmax chunks

typedef __attribute__((ext_vector_type(4))) float f4;

__device__ __forceinline__ float sigm(float x){ return 1.0f/(1.0f+__expf(-x)); }
__device__ __forceinline__ float hsum(f4 v){ return (v.x + v.y) + (v.z + v.w); }

// ---------------- prep kernels ----------------
__global__ __launch_bounds__(256) void k_transpose_t(float* __restrict__ dst,
                                                     const float* __restrict__ src,
                                                     int N, int K){
  __shared__ float tile[32][33];
  int jb = blockIdx.x*32, kb = blockIdx.y*32;
  int tj = threadIdx.x & 31, tk = threadIdx.x >> 5;
  #pragma unroll
  for (int p = 0; p < 4; ++p){
    int j = jb + tk + p*8, k = kb + tj;
    if (j < N && k < K) tile[tk + p*8][tj] = src[j*K + k];
  }
  __syncthreads();
  #pragma unroll
  for (int p = 0; p < 4; ++p){
    int k = kb + tk + p*8, j = jb + tj;
    if (j < N && k < K) dst[k*N + j] = tile[tj][tk + p*8];
  }
}

__global__ __launch_bounds__(256) void k_ghead(float* __restrict__ dst,
                                               const float* __restrict__ W_head){
  int idx = blockIdx.x*256 + threadIdx.x;     // col*512 + k
  if (idx >= 520*512) return;
  int col = idx >> 9, k = idx & 511;
  float v = 0.f;
  if (col < NCOL){ int n = col/129, c = col%129; v = W_head[((size_t)n*2115 + c)*512 + k]; }
  dst[idx] = v;
}

__global__ __launch_bounds__(256) void k_xt(f4* __restrict__ XT4,
                                            const float* __restrict__ x){
  int idx = blockIdx.x*256 + threadIdx.x;     // t*2048 + k4*32 + b
  int b = idx & 31, k4 = (idx >> 5) & 63, t = idx >> 11;
  XT4[idx] = ((const f4*)x)[(size_t)(b*T + t)*64 + k4];
}

// ---------------- PH_A: gates GEMM + LSTM (256 blocks) ----------------
__global__ __launch_bounds__(256) void k_A(
    const f4* __restrict__ XT4, const float* __restrict__ W_ih,
    const float* __restrict__ W_hh, const float* __restrict__ b_ih,
    const float* __restrict__ b_hh, const f4* __restrict__ READT4,
    float* __restrict__ HHT, float* __restrict__ CF, int t)
{
  __shared__ f4 WS[8*256];     // 8 rows x (128 f4 W_ih + 128 f4 W_hh) = 32 KB
  __shared__ float gl[8][33];
  const int bid = blockIdx.x, tid = threadIdx.x;
  const f4* HHT4 = (const f4*)HHT;
  for (int idx = tid; idx < 2048; idx += 256){
    int rsub = idx >> 8, q = idx & 255;
    int gate = rsub & 3, jj = (rsub >> 2) & 1;
    int row = gate*512 + bid*2 + jj;
    WS[idx] = (q < 128) ? ((const f4*)W_ih)[(size_t)row*128 + q]
                        : ((const f4*)W_hh)[(size_t)row*128 + (q - 128)];
  }
  __syncthreads();
  {
    int b = tid & 31, rsub = tid >> 5;
    const f4* w = WS + rsub*256;
    const f4* xt4 = XT4 + (size_t)t*2048;
    f4 a0 = {0.f,0.f,0.f,0.f}, a1 = {0.f,0.f,0.f,0.f};
    #pragma unroll 4
    for (int k4 = 0; k4 < 64; k4 += 2){
      a0 += w[k4]     * xt4[k4*32 + b];
      a1 += w[k4+1]   * xt4[(k4+1)*32 + b];
    }
    #pragma unroll 4
    for (int k4 = 0; k4 < 64; k4 += 2){
      a0 += w[64+k4]   * READT4[k4*32 + b];
      a1 += w[64+k4+1] * READT4[(k4+1)*32 + b];
    }
    if (t > 0){
      const f4* ht4 = HHT4 + (size_t)(t-1)*4096;
      #pragma unroll 4
      for (int k4 = 0; k4 < 128; k4 += 2){
        a0 += w[128+k4]   * ht4[k4*32 + b];
        a1 += w[128+k4+1] * ht4[(k4+1)*32 + b];
      }
    }
    int gate = rsub & 3, jj = rsub >> 2;
    int row = gate*512 + bid*2 + jj;
    gl[rsub][b] = hsum(a0 + a1) + b_ih[row] + b_hh[row];
  }
  __syncthreads();
  if (tid < 64){
    int b2 = tid & 31, jj2 = tid >> 5;
    int j2 = bid*2 + jj2;
    float gi = gl[jj2*4+0][b2], gf = gl[jj2*4+1][b2];
    float gg = gl[jj2*4+2][b2], go = gl[jj2*4+3][b2];
    float c = sigm(gf)*CF[b2*512+j2] + sigm(gi)*tanhf(gg);
    float h = sigm(go)*tanhf(c);
    CF[b2*512+j2] = c;
    HHT[((size_t)t*128 + (j2>>2))*128 + b2*4 + (j2&3)] = h;
  }
}

// ---------------- PH_B: head projection (130 blocks) ----------------
__global__ __launch_bounds__(256) void k_B(
    const float* __restrict__ HHT, const float* __restrict__ WT_HD2,
    const float* __restrict__ b_head, float* __restrict__ HPT, int t)
{
  __shared__ float red[256];
  const int bid = blockIdx.x, tid = threadIdx.x;
  const f4* HHT4 = (const f4*)HHT;
  int b = tid & 31, cs = (tid>>5)&3, khalf = tid>>7;
  int col = bid*4 + cs;
  const f4* hT4 = HHT4 + (size_t)t*4096 + khalf*2048;
  const f4* w4  = (const f4*)(WT_HD2 + (size_t)col*512 + khalf*256);
  f4 acc4 = {0.f, 0.f, 0.f, 0.f};
  #pragma unroll 4
  for (int k4 = 0; k4 < 64; ++k4)
    acc4 += w4[k4] * hT4[k4*32 + b];
  red[tid] = hsum(acc4);
  __syncthreads();
  if (khalf == 0){
    float v = red[tid] + red[tid + 128];
    if (col < NCOL){ int n = col/129, c = col%129; v += b_head[n*2115 + c]; }
    HPT[col*32 + b] = v;
  }
}

// ---- PH_CD: deferred mem-update + scores + partials + partial reads (256 blocks) ----
__global__ __launch_bounds__(256) void k_CD(
    float* __restrict__ MEM, const float* __restrict__ HPT,
    float* __restrict__ SW, float* __restrict__ PART, float* __restrict__ PREAD,
    const float* __restrict__ WST, const float* __restrict__ WKS, int t)
{
  __shared__ float keys[8][64];
  __shared__ float mc[64][68];
  __shared__ float sc[8][64];
  __shared__ float red[8][32];
  __shared__ float cmx[8];
  __shared__ float ew[4][64];
  __shared__ f4 wkp[4][16];
  __shared__ float gmp[4], facp[4];
  const int bid = blockIdx.x, tid = threadIdx.x;
  f4* MEM4 = (f4*)MEM;
  int xcd = bid & 7, t2 = bid >> 3;
  int b = xcd*4 + (t2 & 3), ch8 = t2 >> 2;
  for (int idx = tid; idx < 512; idx += 256){
    int kk = idx >> 6, e = idx & 63;
    int n = kk & 3;
    int c = (kk >= 4) ? (64 + e) : e;
    keys[kk][e] = HPT[(n*129 + c)*32 + b];
  }
  if (t > 0){
    if (tid < 64){
      int n = tid >> 4, e4 = tid & 15;
      wkp[n][e4] = ((const f4*)WKS)[(b*4 + n)*16 + e4];
    }
    if (tid < 4){ gmp[tid] = WST[b*8 + tid*2]; facp[tid] = WST[b*8 + tid*2 + 1]; }
  }
  for (int sub = 0; sub < 4; ++sub){
    int ch = ch8*4 + sub;
    __syncthreads();
    for (int idx = tid; idx < 64*16; idx += 256){
      int m = idx >> 4, e4 = idx & 15;
      ((f4*)&mc[m][0])[e4] = MEM4[((size_t)b*MS + ch*64 + m)*16 + e4];
    }
    if (t > 0){
      // ew from step t-1's scores (SW not yet overwritten for this chunk)
      int n = tid >> 6, m = tid & 63;
      float s = SW[((size_t)b*4 + n)*MS + ch*64 + m];
      ew[n][m] = __expf(s - gmp[n]) * facp[n];
    }
    __syncthreads();
    if (t > 0){
      for (int idx = tid; idx < 1024; idx += 256){
        int m = idx >> 4, e4 = idx & 15;
        f4 v = ((f4*)&mc[m][0])[e4];
        v += ew[0][m]*wkp[0][e4] + ew[1][m]*wkp[1][e4]
           + ew[2][m]*wkp[2][e4] + ew[3][m]*wkp[3][e4];
        ((f4*)&mc[m][0])[e4] = v;
        MEM4[((size_t)b*MS + ch*64 + m)*16 + e4] = v;
      }
      __syncthreads();
    }
    {
      int m = tid & 63, kp = tid >> 6;
      const f4* mrow4 = (const f4*)&mc[m][0];
      int k0 = kp*2, k1 = kp*2+1;
      f4 s0v = {0.f,0.f,0.f,0.f}, s1v = {0.f,0.f,0.f,0.f};
      #pragma unroll 4
      for (int e4 = 0; e4 < 16; ++e4){
        f4 mv = mrow4[e4];
        s0v += mv * (*(const f4*)&keys[k0][e4*4]);
        s1v += mv * (*(const f4*)&keys[k1][e4*4]);
      }
      float s0 = hsum(s0v)*0.125f, s1 = hsum(s1v)*0.125f;
      sc[k0][m] = s0; sc[k1][m] = s1;
      if (kp >= 2){
        float* swp = SW + ((size_t)b*4 + (k0-4))*MS + ch*64 + m;
        swp[0] = s0; swp[MS] = s1;
      }
    }
    __syncthreads();
    {
      int kk = tid >> 5, j = tid & 31;
      red[kk][j] = fmaxf(sc[kk][j], sc[kk][j+32]);
    }
    __syncthreads();
    if (tid < 8){
      float mx = red[tid][0];
      for (int j = 1; j < 32; ++j) mx = fmaxf(mx, red[tid][j]);
      cmx[tid] = mx;
    }
    __syncthreads();
    {
      int kk = tid >> 5, j = tid & 31;
      float m0 = cmx[kk];
      float e0 = __expf(sc[kk][j] - m0);
      float e1 = __expf(sc[kk][j+32] - m0);
      if (kk < 4){ sc[kk][j] = e0; sc[kk][j+32] = e1; }
      red[kk][j] = e0 + e1;
    }
    __syncthreads();
    if (tid < 8){
      float s = 0.f;
      for (int j = 0; j < 32; ++j) s += red[tid][j];
      float* pp = PART + (((size_t)b*NCH + ch)*8 + tid)*2;
      pp[0] = cmx[tid]; pp[1] = s;
    }
    {
      int n = tid >> 6, e = tid & 63;
      float pr = 0.f;
      for (int m = 0; m < 64; ++m) pr += sc[n][m] * mc[m][e];
      PREAD[(((size_t)b*NCH + ch)*4 + n)*64 + e] = pr;
    }
  }
}

// ---- PH_Dlite: read merge + write-side stats + wk save (+HF copy) (32 blocks) ----
__global__ __launch_bounds__(256) void k_Dlite(
    const float* __restrict__ HPT, const float* __restrict__ PART,
    const float* __restrict__ PREAD, float* __restrict__ READT,
    float* __restrict__ RHIST, float* __restrict__ WST, float* __restrict__ WKS,
    const float* __restrict__ HHT, float* __restrict__ HF, int t)
{
  __shared__ float gm2[4], dn2[4];
  const int bid = blockIdx.x, tid = threadIdx.x;
  const f4* HHT4 = (const f4*)HHT;
  int b = bid;
  if (tid < 4){
    // write-side stats -> WST for next step's deferred update
    int kk = 4 + tid;
    const float* pp = PART + ((size_t)b*NCH*8 + kk)*2;
    float mx = -1e30f;
    for (int ch = 0; ch < NCH; ++ch) mx = fmaxf(mx, pp[ch*16]);
    float d = 0.f;
    for (int ch = 0; ch < NCH; ++ch) d += pp[ch*16+1]*__expf(pp[ch*16] - mx);
    float st = sigm(HPT[(tid*129 + 128)*32 + b]);
    WST[b*8 + tid*2]     = mx;
    WST[b*8 + tid*2 + 1] = st / d;
  }
  {
    // save raw write keys (HPT will be overwritten next step)
    int n = tid >> 6, e = tid & 63;
    WKS[(b*4 + n)*64 + e] = HPT[(n*129 + 64 + e)*32 + b];
  }
  if (tid < 4){
    const float* pp = PART + ((size_t)b*NCH*8 + tid)*2;
    float mx = -1e30f;
    for (int ch = 0; ch < NCH; ++ch) mx = fmaxf(mx, pp[ch*16]);
    float d = 0.f;
    for (int ch = 0; ch < NCH; ++ch) d += pp[ch*16+1]*__expf(pp[ch*16] - mx);
    gm2[tid] = mx; dn2[tid] = d;
  }
  __syncthreads();
  {
    int n = tid >> 6, e = tid & 63;
    float gmn = gm2[n], dnn = dn2[n];
    float r = 0.f;
    for (int ch = 0; ch < NCH; ++ch){
      float cm = PART[(((size_t)b*NCH + ch)*8 + n)*2];
      r += PREAD[(((size_t)b*NCH + ch)*4 + n)*64 + e] * __expf(cm - gmn);
    }
    r /= dnn;
    int k = n*64 + e;
    READT[(k>>2)*128 + b*4 + (k&3)] = r;
    RHIST[((size_t)t*64 + (k>>2))*128 + b*4 + (k&3)] = r;
  }
  if (t == T-1){
    int i = bid*256 + tid;       // 8192 slots, need 4096 f4
    if (i < 4096){
      int j4 = i & 127, bb = i >> 7;
      ((f4*)HF)[i] = HHT4[((size_t)(T-1)*128 + j4)*32 + bb];
    }
  }
}

// ---------------- final mem-update flush for t = T-1 (256 blocks) ----------------
__global__ __launch_bounds__(256) void k_flush(
    float* __restrict__ MEM, const float* __restrict__ SW,
    const float* __restrict__ WST, const float* __restrict__ WKS)
{
  __shared__ float gm[4], fac[4];
  __shared__ f4 wk4[4][16];
  __shared__ float ew[4][256];
  const int bid = blockIdx.x, tid = threadIdx.x;
  int xcd = bid & 7, t2 = bid >> 3;
  int b = xcd*4 + (t2 & 3), sub = t2 >> 2;     // 4 chunks of 256 rows
  if (tid < 4){ gm[tid] = WST[b*8 + tid*2]; fac[tid] = WST[b*8 + tid*2 + 1]; }
  if (tid < 64){
    int n = tid >> 4, e4 = tid & 15;
    wk4[n][e4] = ((const f4*)WKS)[(b*4 + n)*16 + e4];
  }
  __syncthreads();
  for (int idx = tid; idx < 1024; idx += 256){
    int n = idx >> 8, m = idx & 255;
    float s = SW[((size_t)b*4 + n)*MS + sub*256 + m];
    ew[n][m] = __expf(s - gm[n]) * fac[n];
  }
  __syncthreads();
  {
    int e4 = tid & 15, ms = tid >> 4;
    f4 k0 = wk4[0][e4], k1 = wk4[1][e4], k2 = wk4[2][e4], k3 = wk4[3][e4];
    #pragma unroll 2
    for (int it = 0; it < 16; ++it){
      int m = it*16 + ms;
      float w0 = ew[0][m], w1 = ew[1][m];
      float w2 = ew[2][m], w3 = ew[3][m];
      f4* p = (f4*)MEM + ((size_t)b*MS + sub*256 + m)*16 + e4;
      f4 v = *p;
      v += w0*k0 + w1*k1 + w2*k2 + w3*k3;
      *p = v;
    }
  }
}

// ---------------- final output GEMM (256 blocks) ----------------
__global__ __launch_bounds__(256) void k_out(
    const float* __restrict__ HHT, const float* __restrict__ RHIST,
    const float* __restrict__ WT_OUT, const float* __restrict__ b_out,
    float* __restrict__ out)
{
  __shared__ float A[16][260];
  const int bid = blockIdx.x, tid = threadIdx.x;
  const f4* HHT4 = (const f4*)HHT;
  const f4* RHIST4 = (const f4*)RHIST;
  const f4* W4 = (const f4*)WT_OUT;
  int nt = bid & 3, mt = bid >> 2;
  int rl = tid & 15, og = tid >> 4;
  int o = nt*64 + og*4, o4 = o >> 2;
  f4 a0 = {0.f,0.f,0.f,0.f}, a1 = a0, a2 = a0, a3 = a0;
  for (int kc = 0; kc < 3; ++kc){
    __syncthreads();
    for (int idx = tid; idx < 1024; idx += 256){
      int r = idx >> 6, k4 = idx & 63;
      int row = mt*16 + r;
      int bb = row >> 5, tt = row & 31;
      int kg4 = kc*64 + k4;
      f4 v = (kg4 < 128)
        ? HHT4[((size_t)tt*128 + kg4)*32 + bb]
        : RHIST4[((size_t)tt*64 + (kg4-128))*32 + bb];
      *(f4*)&A[r][k4*4] = v;
    }
    __syncthreads();
    const float* Ar = &A[rl][0];
    const f4* wp = W4 + (size_t)kc*256*64 + o4;
    #pragma unroll 2
    for (int k = 0; k < 256; k += 4){
      a0 += Ar[k]   * wp[(size_t)(k)*64];
      a1 += Ar[k+1] * wp[(size_t)(k+1)*64];
      a2 += Ar[k+2] * wp[(size_t)(k+2)*64];
      a3 += Ar[k+3] * wp[(size_t)(k+3)*64];
    }
  }
  int row = mt*16 + rl;
  f4 accv = (a0 + a1) + (a2 + a3);
  accv += *(const f4*)(b_out + o);
  *(f4*)(out + (size_t)row*O_DIM + o) = accv;
}

extern "C" void kernel_launch(void* const* d_in, const int* in_sizes, int n_in,
                              void* d_out, int out_size, void* d_ws, size_t ws_size,
                              hipStream_t stream)
{
  const float* x      = (const float*)d_in[0];
  const float* W_ih   = (const float*)d_in[1];
  const float* W_hh   = (const float*)d_in[2];
  const float* b_ih   = (const float*)d_in[3];
  const float* b_hh   = (const float*)d_in[4];
  const float* W_head = (const float*)d_in[5];
  const float* b_head = (const float*)d_in[6];
  const float* W_out  = (const float*)d_in[7];
  const float* b_out  = (const float*)d_in[8];

  float* out = (float*)d_out;
  float* MEM = out + B*T*O_DIM;
  float* HF  = MEM + (size_t)B*MS*HS;
  float* CF  = HF + B*H_DIM;

  float* ws      = (float*)d_ws;
  float* WT_HD2  = ws;                          // 520*512   = 266240
  float* WT_OUT  = WT_HD2 + 520*512;            // 768*256   = 196608
  float* XT      = WT_OUT + 768*256;            // 262144
  float* SW      = XT     + 262144;             // 32*4*2048 = 262144
  float* PART    = SW     + 262144;             // 32*32*8*2 = 16384
  float* PREAD   = PART   + 16384;              // 32*32*4*64= 262144
  float* HPT     = PREAD  + 262144;             // 520*32    = 16640
  float* READT   = HPT    + 16640;              // 256*32    = 8192
  float* HHT     = READT  + 8192;               // 32*512*32 = 524288
  float* RHIST   = HHT    + 524288;             // 32*256*32 = 262144
  float* WST     = RHIST  + 262144;             // 32*8      = 256
  float* WKS     = WST    + 256;                // 32*4*64   = 8192

  (void)hipMemsetAsync(MEM, 0, ((size_t)B*MS*HS + 2*B*H_DIM)*sizeof(float), stream);
  (void)hipMemsetAsync(READT, 0, (size_t)8192*sizeof(float), stream);

  k_ghead<<<1040, 256, 0, stream>>>(WT_HD2, W_head);
  k_transpose_t<<<dim3(8, 24), 256, 0, stream>>>(WT_OUT, W_out, 256, 768);
  k_xt<<<256, 256, 0, stream>>>((f4*)XT, x);

  for (int t = 0; t < T; ++t){
    k_A<<<256, 256, 0, stream>>>((const f4*)XT, W_ih, W_hh, b_ih, b_hh,
                                 (const f4*)READT, HHT, CF, t);
    k_B<<<130, 256, 0, stream>>>(HHT, WT_HD2, b_head, HPT, t);
    k_CD<<<256, 256, 0, stream>>>(MEM, HPT, SW, PART, PREAD, WST, WKS, t);
    k_Dlite<<<32, 256, 0, stream>>>(HPT, PART, PREAD, READT, RHIST, WST, WKS,
                                    HHT, HF, t);
  }
  k_flush<<<256, 256, 0, stream>>>(MEM, SW, WST, WKS);
  k_out<<<256, 256, 0, stream>>>(HHT, RHIST, WT_OUT, b_out, out);
}